// Round 8
// baseline (3018.411 us; speedup 1.0000x reference)
//
#include <hip/hip_runtime.h>

// ---------------- types & helpers ----------------
typedef short short8 __attribute__((ext_vector_type(8)));
typedef float f32x4 __attribute__((ext_vector_type(4)));
typedef unsigned short u16x4 __attribute__((ext_vector_type(4)));

#define MFMA_BF16(a, b, c) __builtin_amdgcn_mfma_f32_16x16x32_bf16((a), (b), (c), 0, 0, 0)

__device__ __forceinline__ float bf2f(unsigned short u) {
    return __uint_as_float(((unsigned)u) << 16);
}
__device__ __forceinline__ unsigned short f2bf(float f) {
    unsigned u = __float_as_uint(f);
    u += 0x7FFFu + ((u >> 16) & 1u);  // round-to-nearest-even
    return (unsigned short)(u >> 16);
}
__device__ __forceinline__ float sigm(float x) { return 1.0f / (1.0f + __expf(-x)); }
__device__ __forceinline__ float tanh_(float x) {
    float e = __expf(-2.0f * fabsf(x));
    float t = (1.0f - e) / (1.0f + e);
    return copysignf(t, x);
}

#define TT 30

// ---------------- weight conversion / packing ----------------
// Regions (elements): Whid_b 65536 | Wih0_b 262144 (row-major) |
//   Wp0 262144 (frag-packed W_hh0) | Wp1 524288 (frag-packed [W_ih1|W_hh1]) |
//   biasC 1024 (b_ih1 + b_hh1)
// Frag-pack: entry ((n*KB + kbi)*64 + L)*8 + e = W[j][k],
//   n = h16*4+g, j = g*256 + h16*16 + (L&15), k = kbi*32 + (L>>4)*8 + e.
__global__ __launch_bounds__(256) void cvt_weights(
    const float* __restrict__ W_hid, const float* __restrict__ W_ih0,
    const float* __restrict__ W_hh0, const float* __restrict__ W_ih1,
    const float* __restrict__ W_hh1, const float* __restrict__ b_ih1,
    const float* __restrict__ b_hh1,
    unsigned short* __restrict__ Whid_b, unsigned short* __restrict__ Wih0_b,
    unsigned short* __restrict__ Wp0, unsigned short* __restrict__ Wp1,
    float* __restrict__ biasC)
{
    int idx = blockIdx.x * 256 + threadIdx.x;
    if (idx < 65536) { Whid_b[idx] = f2bf(W_hid[idx]); return; }
    idx -= 65536;
    if (idx < 262144) {
        int gc = idx >> 8, k = idx & 255;
        Wih0_b[idx] = f2bf(W_ih0[gc * 258 + k]);
        return;
    }
    idx -= 262144;
    if (idx < 262144) {
        int p = idx;
        int e = p & 7, L = (p >> 3) & 63, kbi = (p >> 9) & 7, n = p >> 12;
        int h16 = n >> 2, g = n & 3;
        int j = g * 256 + h16 * 16 + (L & 15);
        int k = kbi * 32 + (L >> 4) * 8 + e;
        Wp0[p] = f2bf(W_hh0[j * 256 + k]);
        return;
    }
    idx -= 262144;
    if (idx < 524288) {
        int p = idx;
        int e = p & 7, L = (p >> 3) & 63, kbi = (p >> 9) & 15, n = p >> 13;
        int h16 = n >> 2, g = n & 3;
        int j = g * 256 + h16 * 16 + (L & 15);
        int k = kbi * 32 + (L >> 4) * 8 + e;
        float v = (k < 256) ? W_ih1[j * 256 + k] : W_hh1[j * 256 + (k - 256)];
        Wp1[p] = f2bf(v);
        return;
    }
    idx -= 524288;
    if (idx < 1024) biasC[idx] = b_ih1[idx] + b_hh1[idx];
}

// combined[n, c] : c<128 obs[b], c<192 lane[b], else ds[kk]
__global__ __launch_bounds__(256) void build_combined(
    const float* __restrict__ obs, const float* __restrict__ lane,
    const float* __restrict__ ds, unsigned short* __restrict__ comb)
{
    int idx = blockIdx.x * 256 + threadIdx.x;  // < 6144*256
    int n = idx >> 8, c = idx & 255;
    int b = n / 6, kk = n - b * 6;
    float v;
    if (c < 128)      v = obs[b * 128 + c];
    else if (c < 192) v = lane[b * 64 + (c - 128)];
    else              v = ds[kk * 64 + (c - 192)];
    comb[idx] = f2bf(v);
}

// ---------------- GEMM: hidden = leakyrelu(combined @ W_hid^T + b_hid) ----------------
__global__ __launch_bounds__(256) void gemm_hidden(
    const unsigned short* __restrict__ A, const unsigned short* __restrict__ B,
    const float* __restrict__ b_hid, unsigned short* __restrict__ hidden)
{
    int wid = threadIdx.x >> 6, lane = threadIdx.x & 63;
    int lrow = lane & 15, kg = lane >> 4;
    int r0 = blockIdx.x * 64;
    int c0 = wid * 64;
    f32x4 acc[4][4];
#pragma unroll
    for (int i = 0; i < 4; i++)
#pragma unroll
        for (int j = 0; j < 4; j++) acc[i][j] = f32x4{0.f, 0.f, 0.f, 0.f};

#pragma unroll
    for (int kb = 0; kb < 256; kb += 32) {
        int k = kb + kg * 8;
        short8 a[4], b[4];
#pragma unroll
        for (int mi = 0; mi < 4; mi++)
            a[mi] = *(const short8*)(A + (size_t)(r0 + mi * 16 + lrow) * 256 + k);
#pragma unroll
        for (int ni = 0; ni < 4; ni++)
            b[ni] = *(const short8*)(B + (size_t)(c0 + ni * 16 + lrow) * 256 + k);
#pragma unroll
        for (int mi = 0; mi < 4; mi++)
#pragma unroll
            for (int ni = 0; ni < 4; ni++)
                acc[mi][ni] = MFMA_BF16(a[mi], b[ni], acc[mi][ni]);
    }
#pragma unroll
    for (int mi = 0; mi < 4; mi++) {
#pragma unroll
        for (int ni = 0; ni < 4; ni++) {
            int col = c0 + ni * 16 + lrow;
            float bb = b_hid[col];
#pragma unroll
            for (int r = 0; r < 4; r++) {
                int row = r0 + mi * 16 + kg * 4 + r;
                float x = acc[mi][ni][r] + bb;
                x = x >= 0.f ? x : 0.1f * x;
                hidden[(size_t)row * 256 + col] = f2bf(x);
            }
        }
    }
}

// ---------------- endpoint / conf head (thread per row) ----------------
__global__ __launch_bounds__(256) void head_kernel(
    const unsigned short* __restrict__ hidden, const float* __restrict__ W_ep,
    const float* __restrict__ b_ep, const float* __restrict__ W_conf,
    const float* __restrict__ b_conf, float* __restrict__ out_conf,
    float* __restrict__ out_ep, float* __restrict__ ep_buf)
{
    int n = blockIdx.x * 256 + threadIdx.x;  // < 6144
    const unsigned short* hr = hidden + (size_t)n * 256;
    float e0 = 0.f, e1 = 0.f, cf = 0.f;
    for (int k = 0; k < 256; k += 8) {
        short8 hv = *(const short8*)(hr + k);
#pragma unroll
        for (int i = 0; i < 8; i++) {
            float h = bf2f((unsigned short)hv[i]);
            e0 += h * W_ep[k + i];
            e1 += h * W_ep[256 + k + i];
            cf += h * W_conf[k + i];
        }
    }
    e0 += b_ep[0]; e1 += b_ep[1]; cf += b_conf[0];
    out_conf[n] = cf;
    out_ep[2 * n] = e0; out_ep[2 * n + 1] = e1;
    ep_buf[2 * n] = e0; ep_buf[2 * n + 1] = e1;
}

// ---------------- GEMM: gx0 (b_ih0+b_hh0 folded, ep rank-2), bf16 frag-layout out ----
// Persistent block pb owns rows [pb*32, pb*32+32). Write:
// gxs4[((pb*8 + wv)*16 + ((mi&1)*2+ni2)*4 + g)*64 + lane], pb = bx*2 + (mi>>1).
__global__ __launch_bounds__(256) void gemm_gx0(
    const unsigned short* __restrict__ A, const unsigned short* __restrict__ B,
    const float* __restrict__ W_ih0f, const float* __restrict__ b_ih0,
    const float* __restrict__ b_hh0, const float* __restrict__ ep_buf,
    u16x4* __restrict__ gxs4)
{
    int wid = threadIdx.x >> 6, lane = threadIdx.x & 63;
    int lrow = lane & 15, kg = lane >> 4;
    int r0 = blockIdx.x * 64;
    int g  = blockIdx.y;                   // gate
    int c0 = g * 256 + wid * 64;
    f32x4 acc[4][4];
#pragma unroll
    for (int i = 0; i < 4; i++)
#pragma unroll
        for (int j = 0; j < 4; j++) acc[i][j] = f32x4{0.f, 0.f, 0.f, 0.f};

#pragma unroll
    for (int kb = 0; kb < 256; kb += 32) {
        int k = kb + kg * 8;
        short8 a[4], b[4];
#pragma unroll
        for (int mi = 0; mi < 4; mi++)
            a[mi] = *(const short8*)(A + (size_t)(r0 + mi * 16 + lrow) * 256 + k);
#pragma unroll
        for (int ni = 0; ni < 4; ni++)
            b[ni] = *(const short8*)(B + (size_t)(c0 + ni * 16 + lrow) * 256 + k);
#pragma unroll
        for (int mi = 0; mi < 4; mi++)
#pragma unroll
            for (int ni = 0; ni < 4; ni++)
                acc[mi][ni] = MFMA_BF16(a[mi], b[ni], acc[mi][ni]);
    }
#pragma unroll
    for (int mi = 0; mi < 4; mi++) {
#pragma unroll
        for (int ni = 0; ni < 4; ni++) {
            int gc = c0 + ni * 16 + lrow;
            float w256 = W_ih0f[(size_t)gc * 258 + 256];
            float w257 = W_ih0f[(size_t)gc * 258 + 257];
            float bb = b_ih0[gc] + b_hh0[gc];
            int h16 = wid * 4 + ni;
            int wv = h16 >> 1, ni2 = h16 & 1;
            int pb = blockIdx.x * 2 + (mi >> 1);
            int idx16 = ((mi & 1) * 2 + ni2) * 4 + g;
            u16x4 pv;
#pragma unroll
            for (int r = 0; r < 4; r++) {
                int row = r0 + mi * 16 + kg * 4 + r;
                float v = acc[mi][ni][r] + bb + ep_buf[2 * row] * w256 + ep_buf[2 * row + 1] * w257;
                pv[r] = f2bf(v);
            }
            gxs4[(size_t)((pb * 8 + wv) * 16 + idx16) * 64 + lane] = pv;
        }
    }
}

// ---------------- persistent 30-step LSTM --------
// 192 blocks x 512 threads (8 waves). Block owns 32 rows. Wave w: hcols [w*32, w*32+32).
// Design goal this round: fit under the allocator's 128-VGPR ceiling with ZERO spill.
//  - c0/c1 live in LDS (not registers): -32 regs
//  - L1 bias reloaded per iter from biasC (L2-hot): -8 regs
//  - gx reloaded per iter from gxs4 (L2-hot): no gxr[32]
//  - loop peeled: branch-free steady body i=2..29
// LDS 128 KB: h0 pp @0/16KB, h1 pp @32/48KB (bf16, XOR swizzle col^((row&7)<<3));
//             c0 @64KB, c1 @96KB (f32, layout [col][row^((col&7)<<2)]).
__global__ __launch_bounds__(512, 1) __attribute__((amdgpu_waves_per_eu(1, 2)))
void lstm_persistent(
    const unsigned short* __restrict__ Wp0, const unsigned short* __restrict__ Wp1,
    const u16x4* __restrict__ gxs4, const float* __restrict__ biasC,
    const float* __restrict__ W_op, const float* __restrict__ b_op,
    float* __restrict__ out_final)
{
    __shared__ unsigned short lds[65536];   // 128 KB

    const int blk  = blockIdx.x;            // rows blk*32 .. +32
    const int w    = threadIdx.x >> 6;
    const int lane = threadIdx.x & 63;
    const int lrow = lane & 15;
    const int kg   = lane >> 4;
    const int sw   = (lrow & 7) << 3;       // A-frag k-swizzle

    const unsigned short* wp0w = Wp0 + (size_t)w * 8 * 4096 + (size_t)lane * 8;
    const unsigned short* wp1w = Wp1 + (size_t)w * 8 * 8192 + (size_t)lane * 8;
    const u16x4* gxw = gxs4 + (size_t)(blk * 8 + w) * 16 * 64 + lane;
    float* cb0 = (float*)&lds[32768];       // c0: 8192 f32
    float* cb1 = cb0 + 8192;                // c1: 8192 f32

    // ---------- phase A (L0 step i) ----------
    auto stepA = [&](int i, bool domfma, bool cinit) {
        unsigned short* h0new = lds + (i & 1) * 8192;
        const unsigned short* h0prev = lds + ((i - 1) & 1) * 8192;
#pragma unroll
        for (int half = 0; half < 2; half++) {
            f32x4 acc[2][4];
#pragma unroll
            for (int mi = 0; mi < 2; mi++)
#pragma unroll
                for (int n = 0; n < 4; n++) acc[mi][n] = f32x4{0.f, 0.f, 0.f, 0.f};
            if (domfma) {
#pragma unroll
                for (int kbi = 0; kbi < 8; kbi++) {
                    short8 a[2], b[4];
#pragma unroll
                    for (int mi = 0; mi < 2; mi++) {
                        int k = (kbi * 32 + kg * 8) ^ sw;
                        a[mi] = *(const short8*)&h0prev[(mi * 16 + lrow) * 256 + k];
                    }
#pragma unroll
                    for (int g = 0; g < 4; g++)
                        b[g] = *(const short8*)&wp0w[(size_t)(((half * 4 + g) * 8 + kbi) * 64) * 8];
#pragma unroll
                    for (int mi = 0; mi < 2; mi++)
#pragma unroll
                        for (int g = 0; g < 4; g++)
                            acc[mi][g] = MFMA_BF16(a[mi], b[g], acc[mi][g]);
                }
            }
            u16x4 gv[8];
#pragma unroll
            for (int mi = 0; mi < 2; mi++)
#pragma unroll
                for (int g = 0; g < 4; g++)
                    gv[mi * 4 + g] = gxw[(size_t)(((mi * 2 + half) * 4 + g) * 64)];
            int col = w * 32 + half * 16 + lrow;
#pragma unroll
            for (int mi = 0; mi < 2; mi++) {
                int rowb = mi * 16 + kg * 4;
                int ci = col * 32 + (rowb ^ ((col & 7) << 2));
                f32x4 cp;
                if (cinit) cp = f32x4{0.f, 0.f, 0.f, 0.f};
                else       cp = *(const f32x4*)&cb0[ci];
                f32x4 cnv;
#pragma unroll
                for (int r = 0; r < 4; r++) {
                    float gi = acc[mi][0][r] + bf2f(gv[mi * 4 + 0][r]);
                    float gf = acc[mi][1][r] + bf2f(gv[mi * 4 + 1][r]);
                    float gg = acc[mi][2][r] + bf2f(gv[mi * 4 + 2][r]);
                    float go = acc[mi][3][r] + bf2f(gv[mi * 4 + 3][r]);
                    float cn = sigm(gf) * cp[r] + sigm(gi) * tanh_(gg);
                    float hn = sigm(go) * tanh_(cn);
                    cnv[r] = cn;
                    int row = rowb + r;
                    h0new[row * 256 + (col ^ ((row & 7) << 3))] = f2bf(hn);
                }
                *(f32x4*)&cb0[ci] = cnv;
            }
        }
    };

    // ---------- phase B (L1 step i-1) ----------
    auto stepB = [&](int i, bool withH1) {
        const unsigned short* h0prev = lds + ((i - 1) & 1) * 8192;
        const unsigned short* h1prev = lds + 16384 + (i & 1) * 8192;
        unsigned short* h1new = lds + 16384 + ((i - 1) & 1) * 8192;
#pragma unroll
        for (int half = 0; half < 2; half++) {
            f32x4 acc[2][4];
#pragma unroll
            for (int mi = 0; mi < 2; mi++)
#pragma unroll
                for (int n = 0; n < 4; n++) acc[mi][n] = f32x4{0.f, 0.f, 0.f, 0.f};
#pragma unroll
            for (int kbi = 0; kbi < 8; kbi++) {
                short8 a[2], b[4];
#pragma unroll
                for (int mi = 0; mi < 2; mi++) {
                    int k = (kbi * 32 + kg * 8) ^ sw;
                    a[mi] = *(const short8*)&h0prev[(mi * 16 + lrow) * 256 + k];
                }
#pragma unroll
                for (int g = 0; g < 4; g++)
                    b[g] = *(const short8*)&wp1w[(size_t)(((half * 4 + g) * 16 + kbi) * 64) * 8];
#pragma unroll
                for (int mi = 0; mi < 2; mi++)
#pragma unroll
                    for (int g = 0; g < 4; g++)
                        acc[mi][g] = MFMA_BF16(a[mi], b[g], acc[mi][g]);
            }
            if (withH1) {
#pragma unroll
                for (int kbi = 0; kbi < 8; kbi++) {
                    short8 a[2], b[4];
#pragma unroll
                    for (int mi = 0; mi < 2; mi++) {
                        int k = (kbi * 32 + kg * 8) ^ sw;
                        a[mi] = *(const short8*)&h1prev[(mi * 16 + lrow) * 256 + k];
                    }
#pragma unroll
                    for (int g = 0; g < 4; g++)
                        b[g] = *(const short8*)&wp1w[(size_t)(((half * 4 + g) * 16 + 8 + kbi) * 64) * 8];
#pragma unroll
                    for (int mi = 0; mi < 2; mi++)
#pragma unroll
                        for (int g = 0; g < 4; g++)
                            acc[mi][g] = MFMA_BF16(a[mi], b[g], acc[mi][g]);
                }
            }
            int col = w * 32 + half * 16 + lrow;
            float bI = biasC[col];
            float bF = biasC[256 + col];
            float bG = biasC[512 + col];
            float bO = biasC[768 + col];
#pragma unroll
            for (int mi = 0; mi < 2; mi++) {
                int rowb = mi * 16 + kg * 4;
                int ci = col * 32 + (rowb ^ ((col & 7) << 2));
                f32x4 cp;
                if (withH1) cp = *(const f32x4*)&cb1[ci];
                else        cp = f32x4{0.f, 0.f, 0.f, 0.f};
                f32x4 cnv;
#pragma unroll
                for (int r = 0; r < 4; r++) {
                    float gi = acc[mi][0][r] + bI;
                    float gf = acc[mi][1][r] + bF;
                    float gg = acc[mi][2][r] + bG;
                    float go = acc[mi][3][r] + bO;
                    float cn = sigm(gf) * cp[r] + sigm(gi) * tanh_(gg);
                    float hn = sigm(go) * tanh_(cn);
                    cnv[r] = cn;
                    int row = rowb + r;
                    h1new[row * 256 + (col ^ ((row & 7) << 3))] = f2bf(hn);
                }
                *(f32x4*)&cb1[ci] = cnv;
            }
        }
    };

    // ---------- out-projection: t = i-2 ----------
    auto proj = [&](int i) {
        const unsigned short* h1t = lds + 16384 + (i & 1) * 8192;
        int prow = threadIdx.x >> 4;
        int pseg = threadIdx.x & 15;
        int psw  = (prow & 7) << 3;
        float p0 = 0.f, p1 = 0.f;
#pragma unroll
        for (int q = 0; q < 2; q++) {
            int col0 = pseg * 16 + q * 8;
            short8 hv = *(const short8*)&h1t[prow * 256 + (col0 ^ psw)];
#pragma unroll
            for (int e = 0; e < 8; e++) {
                float h = bf2f((unsigned short)hv[e]);
                p0 += h * W_op[col0 + e];
                p1 += h * W_op[256 + col0 + e];
            }
        }
#pragma unroll
        for (int s = 1; s < 16; s <<= 1) {
            p0 += __shfl_xor(p0, s, 64);
            p1 += __shfl_xor(p1, s, 64);
        }
        if (pseg == 0) {
            int grow = blk * 32 + prow;
            int t = i - 2;
            out_final[((size_t)grow * TT + t) * 2 + 0] = p0 + b_op[0];
            out_final[((size_t)grow * TT + t) * 2 + 1] = p1 + b_op[1];
        }
    };

    // prologue
    stepA(0, false, true);
    __syncthreads();
    stepA(1, true, false);
    stepB(1, false);
    __syncthreads();
    // steady (branch-free)
    for (int i = 2; i <= 29; ++i) {
        stepA(i, true, false);
        stepB(i, true);
        proj(i);
        __syncthreads();
    }
    // epilogue
    stepB(30, true);
    proj(30);
    __syncthreads();
    proj(31);
}

// ---------------- host ----------------
extern "C" void kernel_launch(void* const* d_in, const int* in_sizes, int n_in,
                              void* d_out, int out_size, void* d_ws, size_t ws_size,
                              hipStream_t stream)
{
    const float* obs    = (const float*)d_in[0];
    const float* lane   = (const float*)d_in[1];
    const float* ds     = (const float*)d_in[3];
    const float* W_hid  = (const float*)d_in[4];
    const float* b_hid  = (const float*)d_in[5];
    const float* W_ep   = (const float*)d_in[6];
    const float* b_ep   = (const float*)d_in[7];
    const float* W_conf = (const float*)d_in[8];
    const float* b_conf = (const float*)d_in[9];
    const float* W_ih0  = (const float*)d_in[10];
    const float* W_hh0  = (const float*)d_in[11];
    const float* b_ih0  = (const float*)d_in[12];
    const float* b_hh0  = (const float*)d_in[13];
    const float* W_ih1  = (const float*)d_in[14];
    const float* W_hh1  = (const float*)d_in[15];
    const float* b_ih1  = (const float*)d_in[16];
    const float* b_hh1  = (const float*)d_in[17];
    const float* W_op   = (const float*)d_in[18];
    const float* b_op   = (const float*)d_in[19];

    float* out_final = (float*)d_out;           // [6144*30*2]
    float* out_conf  = out_final + 368640;      // [6144]
    float* out_ep    = out_conf + 6144;         // [6144*2]

    char* ws = (char*)d_ws;
    size_t off = 0;
    auto alloc = [&](size_t bytes) -> void* {
        void* p = ws + off;
        off += (bytes + 255) & ~(size_t)255;
        return p;
    };
    unsigned short* Whid_b = (unsigned short*)alloc(65536 * 2);
    unsigned short* Wih0_b = (unsigned short*)alloc(262144 * 2);
    unsigned short* Wp0    = (unsigned short*)alloc(262144 * 2);
    unsigned short* Wp1    = (unsigned short*)alloc(524288 * 2);
    float*          biasC  = (float*)alloc(1024 * 4);
    unsigned short* comb_b = (unsigned short*)alloc(1572864 * 2);
    unsigned short* hid_b  = (unsigned short*)alloc(1572864 * 2);
    float* ep_buf = (float*)alloc(12288 * 4);
    u16x4* gxs4   = (u16x4*)alloc((size_t)1572864 * 8);

    cvt_weights<<<4356, 256, 0, stream>>>(W_hid, W_ih0, W_hh0, W_ih1, W_hh1,
                                          b_ih1, b_hh1,
                                          Whid_b, Wih0_b, Wp0, Wp1, biasC);
    build_combined<<<6144, 256, 0, stream>>>(obs, lane, ds, comb_b);
    gemm_hidden<<<96, 256, 0, stream>>>(comb_b, Whid_b, b_hid, hid_b);
    head_kernel<<<24, 256, 0, stream>>>(hid_b, W_ep, b_ep, W_conf, b_conf,
                                        out_conf, out_ep, ep_buf);
    dim3 g2(96, 4);
    gemm_gx0<<<g2, 256, 0, stream>>>(hid_b, Wih0_b, W_ih0, b_ih0, b_hh0, ep_buf, gxs4);

    lstm_persistent<<<192, 512, 0, stream>>>(Wp0, Wp1, gxs4, biasC,
                                             W_op, b_op, out_final);
}

// Round 9
// 1681.852 us; speedup vs baseline: 1.7947x; 1.7947x over previous
//
#include <hip/hip_runtime.h>

// ---------------- types & helpers ----------------
typedef short short8 __attribute__((ext_vector_type(8)));
typedef float f32x4 __attribute__((ext_vector_type(4)));
typedef unsigned short u16x4 __attribute__((ext_vector_type(4)));

#define MFMA_BF16(a, b, c) __builtin_amdgcn_mfma_f32_16x16x32_bf16((a), (b), (c), 0, 0, 0)

__device__ __forceinline__ float bf2f(unsigned short u) {
    return __uint_as_float(((unsigned)u) << 16);
}
__device__ __forceinline__ unsigned short f2bf(float f) {
    unsigned u = __float_as_uint(f);
    u += 0x7FFFu + ((u >> 16) & 1u);  // round-to-nearest-even
    return (unsigned short)(u >> 16);
}
__device__ __forceinline__ float sigm(float x) { return 1.0f / (1.0f + __expf(-x)); }
__device__ __forceinline__ float tanh_(float x) {
    float e = __expf(-2.0f * fabsf(x));
    float t = (1.0f - e) / (1.0f + e);
    return copysignf(t, x);
}

#define TT 30

// ---------------- weight conversion / packing ----------------
// Regions (elements): Whid_b 65536 | Wih0_b 262144 (row-major) |
//   Wp0 262144 (frag-packed W_hh0) | Wp1 524288 (frag-packed [W_ih1|W_hh1]) |
//   biasC 1024 (b_ih1 + b_hh1)
// Frag-pack: entry ((n*KB + kbi)*64 + L)*8 + e = W[j][k],
//   n = h16*4+g, j = g*256 + h16*16 + (L&15), k = kbi*32 + (L>>4)*8 + e.
__global__ __launch_bounds__(256) void cvt_weights(
    const float* __restrict__ W_hid, const float* __restrict__ W_ih0,
    const float* __restrict__ W_hh0, const float* __restrict__ W_ih1,
    const float* __restrict__ W_hh1, const float* __restrict__ b_ih1,
    const float* __restrict__ b_hh1,
    unsigned short* __restrict__ Whid_b, unsigned short* __restrict__ Wih0_b,
    unsigned short* __restrict__ Wp0, unsigned short* __restrict__ Wp1,
    float* __restrict__ biasC)
{
    int idx = blockIdx.x * 256 + threadIdx.x;
    if (idx < 65536) { Whid_b[idx] = f2bf(W_hid[idx]); return; }
    idx -= 65536;
    if (idx < 262144) {
        int gc = idx >> 8, k = idx & 255;
        Wih0_b[idx] = f2bf(W_ih0[gc * 258 + k]);
        return;
    }
    idx -= 262144;
    if (idx < 262144) {
        int p = idx;
        int e = p & 7, L = (p >> 3) & 63, kbi = (p >> 9) & 7, n = p >> 12;
        int h16 = n >> 2, g = n & 3;
        int j = g * 256 + h16 * 16 + (L & 15);
        int k = kbi * 32 + (L >> 4) * 8 + e;
        Wp0[p] = f2bf(W_hh0[j * 256 + k]);
        return;
    }
    idx -= 262144;
    if (idx < 524288) {
        int p = idx;
        int e = p & 7, L = (p >> 3) & 63, kbi = (p >> 9) & 15, n = p >> 13;
        int h16 = n >> 2, g = n & 3;
        int j = g * 256 + h16 * 16 + (L & 15);
        int k = kbi * 32 + (L >> 4) * 8 + e;
        float v = (k < 256) ? W_ih1[j * 256 + k] : W_hh1[j * 256 + (k - 256)];
        Wp1[p] = f2bf(v);
        return;
    }
    idx -= 524288;
    if (idx < 1024) biasC[idx] = b_ih1[idx] + b_hh1[idx];
}

// combined[n, c] : c<128 obs[b], c<192 lane[b], else ds[kk]
__global__ __launch_bounds__(256) void build_combined(
    const float* __restrict__ obs, const float* __restrict__ lane,
    const float* __restrict__ ds, unsigned short* __restrict__ comb)
{
    int idx = blockIdx.x * 256 + threadIdx.x;  // < 6144*256
    int n = idx >> 8, c = idx & 255;
    int b = n / 6, kk = n - b * 6;
    float v;
    if (c < 128)      v = obs[b * 128 + c];
    else if (c < 192) v = lane[b * 64 + (c - 128)];
    else              v = ds[kk * 64 + (c - 192)];
    comb[idx] = f2bf(v);
}

// ---------------- GEMM: hidden = leakyrelu(combined @ W_hid^T + b_hid) ----------------
__global__ __launch_bounds__(256) void gemm_hidden(
    const unsigned short* __restrict__ A, const unsigned short* __restrict__ B,
    const float* __restrict__ b_hid, unsigned short* __restrict__ hidden)
{
    int wid = threadIdx.x >> 6, lane = threadIdx.x & 63;
    int lrow = lane & 15, kg = lane >> 4;
    int r0 = blockIdx.x * 64;
    int c0 = wid * 64;
    f32x4 acc[4][4];
#pragma unroll
    for (int i = 0; i < 4; i++)
#pragma unroll
        for (int j = 0; j < 4; j++) acc[i][j] = f32x4{0.f, 0.f, 0.f, 0.f};

#pragma unroll
    for (int kb = 0; kb < 256; kb += 32) {
        int k = kb + kg * 8;
        short8 a[4], b[4];
#pragma unroll
        for (int mi = 0; mi < 4; mi++)
            a[mi] = *(const short8*)(A + (size_t)(r0 + mi * 16 + lrow) * 256 + k);
#pragma unroll
        for (int ni = 0; ni < 4; ni++)
            b[ni] = *(const short8*)(B + (size_t)(c0 + ni * 16 + lrow) * 256 + k);
#pragma unroll
        for (int mi = 0; mi < 4; mi++)
#pragma unroll
            for (int ni = 0; ni < 4; ni++)
                acc[mi][ni] = MFMA_BF16(a[mi], b[ni], acc[mi][ni]);
    }
#pragma unroll
    for (int mi = 0; mi < 4; mi++) {
#pragma unroll
        for (int ni = 0; ni < 4; ni++) {
            int col = c0 + ni * 16 + lrow;
            float bb = b_hid[col];
#pragma unroll
            for (int r = 0; r < 4; r++) {
                int row = r0 + mi * 16 + kg * 4 + r;
                float x = acc[mi][ni][r] + bb;
                x = x >= 0.f ? x : 0.1f * x;
                hidden[(size_t)row * 256 + col] = f2bf(x);
            }
        }
    }
}

// ---------------- endpoint / conf head (thread per row) ----------------
__global__ __launch_bounds__(256) void head_kernel(
    const unsigned short* __restrict__ hidden, const float* __restrict__ W_ep,
    const float* __restrict__ b_ep, const float* __restrict__ W_conf,
    const float* __restrict__ b_conf, float* __restrict__ out_conf,
    float* __restrict__ out_ep, float* __restrict__ ep_buf)
{
    int n = blockIdx.x * 256 + threadIdx.x;  // < 6144
    const unsigned short* hr = hidden + (size_t)n * 256;
    float e0 = 0.f, e1 = 0.f, cf = 0.f;
    for (int k = 0; k < 256; k += 8) {
        short8 hv = *(const short8*)(hr + k);
#pragma unroll
        for (int i = 0; i < 8; i++) {
            float h = bf2f((unsigned short)hv[i]);
            e0 += h * W_ep[k + i];
            e1 += h * W_ep[256 + k + i];
            cf += h * W_conf[k + i];
        }
    }
    e0 += b_ep[0]; e1 += b_ep[1]; cf += b_conf[0];
    out_conf[n] = cf;
    out_ep[2 * n] = e0; out_ep[2 * n + 1] = e1;
    ep_buf[2 * n] = e0; ep_buf[2 * n + 1] = e1;
}

// ---------------- GEMM: gx0 (b_ih0+b_hh0 folded, ep rank-2), bf16 frag-layout out ----
// Persistent block pb owns rows [pb*32, pb*32+32). Write:
// gxs4[((pb*8 + wv)*16 + ((mi&1)*2+ni2)*4 + g)*64 + lane], pb = bx*2 + (mi>>1).
__global__ __launch_bounds__(256) void gemm_gx0(
    const unsigned short* __restrict__ A, const unsigned short* __restrict__ B,
    const float* __restrict__ W_ih0f, const float* __restrict__ b_ih0,
    const float* __restrict__ b_hh0, const float* __restrict__ ep_buf,
    u16x4* __restrict__ gxs4)
{
    int wid = threadIdx.x >> 6, lane = threadIdx.x & 63;
    int lrow = lane & 15, kg = lane >> 4;
    int r0 = blockIdx.x * 64;
    int g  = blockIdx.y;                   // gate
    int c0 = g * 256 + wid * 64;
    f32x4 acc[4][4];
#pragma unroll
    for (int i = 0; i < 4; i++)
#pragma unroll
        for (int j = 0; j < 4; j++) acc[i][j] = f32x4{0.f, 0.f, 0.f, 0.f};

#pragma unroll
    for (int kb = 0; kb < 256; kb += 32) {
        int k = kb + kg * 8;
        short8 a[4], b[4];
#pragma unroll
        for (int mi = 0; mi < 4; mi++)
            a[mi] = *(const short8*)(A + (size_t)(r0 + mi * 16 + lrow) * 256 + k);
#pragma unroll
        for (int ni = 0; ni < 4; ni++)
            b[ni] = *(const short8*)(B + (size_t)(c0 + ni * 16 + lrow) * 256 + k);
#pragma unroll
        for (int mi = 0; mi < 4; mi++)
#pragma unroll
            for (int ni = 0; ni < 4; ni++)
                acc[mi][ni] = MFMA_BF16(a[mi], b[ni], acc[mi][ni]);
    }
#pragma unroll
    for (int mi = 0; mi < 4; mi++) {
#pragma unroll
        for (int ni = 0; ni < 4; ni++) {
            int gc = c0 + ni * 16 + lrow;
            float w256 = W_ih0f[(size_t)gc * 258 + 256];
            float w257 = W_ih0f[(size_t)gc * 258 + 257];
            float bb = b_ih0[gc] + b_hh0[gc];
            int h16 = wid * 4 + ni;
            int wv = h16 >> 1, ni2 = h16 & 1;
            int pb = blockIdx.x * 2 + (mi >> 1);
            int idx16 = ((mi & 1) * 2 + ni2) * 4 + g;
            u16x4 pv;
#pragma unroll
            for (int r = 0; r < 4; r++) {
                int row = r0 + mi * 16 + kg * 4 + r;
                float v = acc[mi][ni][r] + bb + ep_buf[2 * row] * w256 + ep_buf[2 * row + 1] * w257;
                pv[r] = f2bf(v);
            }
            gxs4[(size_t)((pb * 8 + wv) * 16 + idx16) * 64 + lane] = pv;
        }
    }
}

// ---------------- persistent 30-step LSTM --------
// 192 blocks x 512 threads (8 waves). Block owns 32 rows. Wave w: hcols [w*32, w*32+32).
// r6 structure (best so far) with two register/L2 fixes:
//  - gx staged into LDS once (64 KB/block); steady-state gx reads are ds_read_b64.
//    -> L2 steady-state residents = weights only (1.5 MB/XCD).
//  - L1-bias read per iter from biasC (4 KB, L1/L2-hot) instead of 8 pinned regs.
// Live set ~111 VGPR < 128 -> zero spill (spill scratch was the L2 polluter r4-r8).
// LDS 128 KB: h0 pp @0/16KB, h1 pp @32/48KB (bf16, XOR swizzle col^((row&7)<<3)),
//             gx @64KB (u16x4[(w*16+j)*64+lane]).
// Iter i: phase A h0[i] (i<=29); phase B h1[i-1] (1<=i<=30); proj t=i-2 (2<=i<=31).
__global__ __launch_bounds__(512, 1) void lstm_persistent(
    const unsigned short* __restrict__ Wp0, const unsigned short* __restrict__ Wp1,
    const u16x4* __restrict__ gxs4, const float* __restrict__ biasC,
    const float* __restrict__ W_op, const float* __restrict__ b_op,
    float* __restrict__ out_final)
{
    __shared__ unsigned short lds[65536];   // 128 KB

    const int blk  = blockIdx.x;            // rows blk*32 .. +32
    const int w    = threadIdx.x >> 6;
    const int lane = threadIdx.x & 63;
    const int lrow = lane & 15;
    const int kg   = lane >> 4;
    const int sw   = (lrow & 7) << 3;       // A-frag k-swizzle

    // stage gx into LDS (once)
    u16x4* gxl = (u16x4*)&lds[32768];
    {
        const u16x4* gxw = gxs4 + (size_t)(blk * 8 + w) * 16 * 64;
#pragma unroll
        for (int j = 0; j < 16; j++)
            gxl[(w * 16 + j) * 64 + lane] = gxw[j * 64 + lane];
    }
    __syncthreads();

    f32x4 c0r[2][2], c1r[2][2];
#pragma unroll
    for (int mi = 0; mi < 2; mi++)
#pragma unroll
        for (int ni2 = 0; ni2 < 2; ni2++) {
            c0r[mi][ni2] = f32x4{0.f, 0.f, 0.f, 0.f};
            c1r[mi][ni2] = f32x4{0.f, 0.f, 0.f, 0.f};
        }

    // per-lane base pointers
    const unsigned short* wp0w = Wp0 + (size_t)w * 8 * 4096 + (size_t)lane * 8;
    const unsigned short* wp1w = Wp1 + (size_t)w * 8 * 8192 + (size_t)lane * 8;

    const int prow = threadIdx.x >> 4;   // 0..31 (proj row)
    const int pseg = threadIdx.x & 15;   // 16 threads/row, 16 cols each
    const int psw  = (prow & 7) << 3;

    for (int i = 0; i < 32; ++i) {
        // ---------- phase A: L0 step i ----------
        if (i <= 29) {
            unsigned short* h0new = lds + (i & 1) * 8192;
            const unsigned short* h0prev = lds + ((i - 1) & 1) * 8192;
#pragma unroll
            for (int half = 0; half < 2; half++) {
                f32x4 acc[2][4];
#pragma unroll
                for (int mi = 0; mi < 2; mi++)
#pragma unroll
                    for (int n = 0; n < 4; n++) acc[mi][n] = f32x4{0.f, 0.f, 0.f, 0.f};
                if (i > 0) {
#pragma unroll
                    for (int kbi = 0; kbi < 8; kbi++) {
                        short8 a[2], b[4];
#pragma unroll
                        for (int mi = 0; mi < 2; mi++) {
                            int k = (kbi * 32 + kg * 8) ^ sw;
                            a[mi] = *(const short8*)&h0prev[(mi * 16 + lrow) * 256 + k];
                        }
#pragma unroll
                        for (int g = 0; g < 4; g++)
                            b[g] = *(const short8*)&wp0w[(size_t)(((half * 4 + g) * 8 + kbi) * 64) * 8];
#pragma unroll
                        for (int mi = 0; mi < 2; mi++)
#pragma unroll
                            for (int g = 0; g < 4; g++)
                                acc[mi][g] = MFMA_BF16(a[mi], b[g], acc[mi][g]);
                    }
                }
                int col = w * 32 + half * 16 + lrow;
#pragma unroll
                for (int mi = 0; mi < 2; mi++) {
                    u16x4 gI = gxl[(w * 16 + (mi * 2 + half) * 4 + 0) * 64 + lane];
                    u16x4 gF = gxl[(w * 16 + (mi * 2 + half) * 4 + 1) * 64 + lane];
                    u16x4 gG = gxl[(w * 16 + (mi * 2 + half) * 4 + 2) * 64 + lane];
                    u16x4 gO = gxl[(w * 16 + (mi * 2 + half) * 4 + 3) * 64 + lane];
#pragma unroll
                    for (int r = 0; r < 4; r++) {
                        float gi = acc[mi][0][r] + bf2f(gI[r]);
                        float gf = acc[mi][1][r] + bf2f(gF[r]);
                        float gg = acc[mi][2][r] + bf2f(gG[r]);
                        float go = acc[mi][3][r] + bf2f(gO[r]);
                        float cn = sigm(gf) * c0r[mi][half][r] + sigm(gi) * tanh_(gg);
                        float hn = sigm(go) * tanh_(cn);
                        c0r[mi][half][r] = cn;
                        int row = mi * 16 + kg * 4 + r;
                        h0new[row * 256 + (col ^ ((row & 7) << 3))] = f2bf(hn);
                    }
                }
            }
        }
        // ---------- phase B: L1 step i-1 ----------
        if (i >= 1 && i <= 30) {
            const unsigned short* h0prev = lds + ((i - 1) & 1) * 8192;
            const unsigned short* h1prev = lds + 16384 + (i & 1) * 8192;
            unsigned short* h1new = lds + 16384 + ((i - 1) & 1) * 8192;
#pragma unroll
            for (int half = 0; half < 2; half++) {
                f32x4 acc[2][4];
#pragma unroll
                for (int mi = 0; mi < 2; mi++)
#pragma unroll
                    for (int n = 0; n < 4; n++) acc[mi][n] = f32x4{0.f, 0.f, 0.f, 0.f};
#pragma unroll
                for (int kbi = 0; kbi < 8; kbi++) {
                    short8 a[2], b[4];
#pragma unroll
                    for (int mi = 0; mi < 2; mi++) {
                        int k = (kbi * 32 + kg * 8) ^ sw;
                        a[mi] = *(const short8*)&h0prev[(mi * 16 + lrow) * 256 + k];
                    }
#pragma unroll
                    for (int g = 0; g < 4; g++)
                        b[g] = *(const short8*)&wp1w[(size_t)(((half * 4 + g) * 16 + kbi) * 64) * 8];
#pragma unroll
                    for (int mi = 0; mi < 2; mi++)
#pragma unroll
                        for (int g = 0; g < 4; g++)
                            acc[mi][g] = MFMA_BF16(a[mi], b[g], acc[mi][g]);
                }
                if (i >= 2) {
#pragma unroll
                    for (int kbi = 0; kbi < 8; kbi++) {
                        short8 a[2], b[4];
#pragma unroll
                        for (int mi = 0; mi < 2; mi++) {
                            int k = (kbi * 32 + kg * 8) ^ sw;
                            a[mi] = *(const short8*)&h1prev[(mi * 16 + lrow) * 256 + k];
                        }
#pragma unroll
                        for (int g = 0; g < 4; g++)
                            b[g] = *(const short8*)&wp1w[(size_t)(((half * 4 + g) * 16 + 8 + kbi) * 64) * 8];
#pragma unroll
                        for (int mi = 0; mi < 2; mi++)
#pragma unroll
                            for (int g = 0; g < 4; g++)
                                acc[mi][g] = MFMA_BF16(a[mi], b[g], acc[mi][g]);
                    }
                }
                int col = w * 32 + half * 16 + lrow;
                float bI = biasC[col];
                float bF = biasC[256 + col];
                float bG = biasC[512 + col];
                float bO = biasC[768 + col];
#pragma unroll
                for (int mi = 0; mi < 2; mi++) {
#pragma unroll
                    for (int r = 0; r < 4; r++) {
                        float gi = acc[mi][0][r] + bI;
                        float gf = acc[mi][1][r] + bF;
                        float gg = acc[mi][2][r] + bG;
                        float go = acc[mi][3][r] + bO;
                        float cn = sigm(gf) * c1r[mi][half][r] + sigm(gi) * tanh_(gg);
                        float hn = sigm(go) * tanh_(cn);
                        c1r[mi][half][r] = cn;
                        int row = mi * 16 + kg * 4 + r;
                        h1new[row * 256 + (col ^ ((row & 7) << 3))] = f2bf(hn);
                    }
                }
            }
        }
        // ---------- out-projection: t = i-2 ----------
        if (i >= 2) {
            const unsigned short* h1t = lds + 16384 + (i & 1) * 8192;
            float p0 = 0.f, p1 = 0.f;
#pragma unroll
            for (int q = 0; q < 2; q++) {
                int col0 = pseg * 16 + q * 8;
                short8 hv = *(const short8*)&h1t[prow * 256 + (col0 ^ psw)];
#pragma unroll
                for (int e = 0; e < 8; e++) {
                    float h = bf2f((unsigned short)hv[e]);
                    p0 += h * W_op[col0 + e];
                    p1 += h * W_op[256 + col0 + e];
                }
            }
#pragma unroll
            for (int s = 1; s < 16; s <<= 1) {
                p0 += __shfl_xor(p0, s, 64);
                p1 += __shfl_xor(p1, s, 64);
            }
            if (pseg == 0) {
                int grow = blk * 32 + prow;
                int t = i - 2;
                out_final[((size_t)grow * TT + t) * 2 + 0] = p0 + b_op[0];
                out_final[((size_t)grow * TT + t) * 2 + 1] = p1 + b_op[1];
            }
        }
        __syncthreads();
    }
}

// ---------------- host ----------------
extern "C" void kernel_launch(void* const* d_in, const int* in_sizes, int n_in,
                              void* d_out, int out_size, void* d_ws, size_t ws_size,
                              hipStream_t stream)
{
    const float* obs    = (const float*)d_in[0];
    const float* lane   = (const float*)d_in[1];
    const float* ds     = (const float*)d_in[3];
    const float* W_hid  = (const float*)d_in[4];
    const float* b_hid  = (const float*)d_in[5];
    const float* W_ep   = (const float*)d_in[6];
    const float* b_ep   = (const float*)d_in[7];
    const float* W_conf = (const float*)d_in[8];
    const float* b_conf = (const float*)d_in[9];
    const float* W_ih0  = (const float*)d_in[10];
    const float* W_hh0  = (const float*)d_in[11];
    const float* b_ih0  = (const float*)d_in[12];
    const float* b_hh0  = (const float*)d_in[13];
    const float* W_ih1  = (const float*)d_in[14];
    const float* W_hh1  = (const float*)d_in[15];
    const float* b_ih1  = (const float*)d_in[16];
    const float* b_hh1  = (const float*)d_in[17];
    const float* W_op   = (const float*)d_in[18];
    const float* b_op   = (const float*)d_in[19];

    float* out_final = (float*)d_out;           // [6144*30*2]
    float* out_conf  = out_final + 368640;      // [6144]
    float* out_ep    = out_conf + 6144;         // [6144*2]

    char* ws = (char*)d_ws;
    size_t off = 0;
    auto alloc = [&](size_t bytes) -> void* {
        void* p = ws + off;
        off += (bytes + 255) & ~(size_t)255;
        return p;
    };
    unsigned short* Whid_b = (unsigned short*)alloc(65536 * 2);
    unsigned short* Wih0_b = (unsigned short*)alloc(262144 * 2);
    unsigned short* Wp0    = (unsigned short*)alloc(262144 * 2);
    unsigned short* Wp1    = (unsigned short*)alloc(524288 * 2);
    float*          biasC  = (float*)alloc(1024 * 4);
    unsigned short* comb_b = (unsigned short*)alloc(1572864 * 2);
    unsigned short* hid_b  = (unsigned short*)alloc(1572864 * 2);
    float* ep_buf = (float*)alloc(12288 * 4);
    u16x4* gxs4   = (u16x4*)alloc((size_t)1572864 * 8);

    cvt_weights<<<4356, 256, 0, stream>>>(W_hid, W_ih0, W_hh0, W_ih1, W_hh1,
                                          b_ih1, b_hh1,
                                          Whid_b, Wih0_b, Wp0, Wp1, biasC);
    build_combined<<<6144, 256, 0, stream>>>(obs, lane, ds, comb_b);
    gemm_hidden<<<96, 256, 0, stream>>>(comb_b, Whid_b, b_hid, hid_b);
    head_kernel<<<24, 256, 0, stream>>>(hid_b, W_ep, b_ep, W_conf, b_conf,
                                        out_conf, out_ep, ep_buf);
    dim3 g2(96, 4);
    gemm_gx0<<<g2, 256, 0, stream>>>(hid_b, Wih0_b, W_ih0, b_ih0, b_hh0, ep_buf, gxs4);

    lstm_persistent<<<192, 512, 0, stream>>>(Wp0, Wp1, gxs4, biasC,
                                             W_op, b_op, out_final);
}

// Round 10
// 1624.018 us; speedup vs baseline: 1.8586x; 1.0356x over previous
//
#include <hip/hip_runtime.h>

// ---------------- types & helpers ----------------
typedef short short8 __attribute__((ext_vector_type(8)));
typedef float f32x4 __attribute__((ext_vector_type(4)));
typedef unsigned short u16x4 __attribute__((ext_vector_type(4)));

#define MFMA_BF16(a, b, c) __builtin_amdgcn_mfma_f32_16x16x32_bf16((a), (b), (c), 0, 0, 0)
// Park a value in the AGPR half of the unified register file (gfx950).
// Empty asm with "+a" forces the live range endpoint into an AGPR, freeing
// arch VGPRs during the MFMA/load-heavy sections. (r4-r9: allocator pins
// arch VGPRs at 128 and spills ~12 regs to scratch; this reclaims them.)
#define PIN_AGPR(x) asm volatile("" : "+a"(x))

__device__ __forceinline__ float bf2f(unsigned short u) {
    return __uint_as_float(((unsigned)u) << 16);
}
__device__ __forceinline__ unsigned short f2bf(float f) {
    unsigned u = __float_as_uint(f);
    u += 0x7FFFu + ((u >> 16) & 1u);  // round-to-nearest-even
    return (unsigned short)(u >> 16);
}
__device__ __forceinline__ float sigm(float x) { return 1.0f / (1.0f + __expf(-x)); }
__device__ __forceinline__ float tanh_(float x) {
    float e = __expf(-2.0f * fabsf(x));
    float t = (1.0f - e) / (1.0f + e);
    return copysignf(t, x);
}

#define TT 30

// ---------------- weight conversion / packing ----------------
// Regions (elements): Whid_b 65536 | Wih0_b 262144 (row-major) |
//   Wp0 262144 (frag-packed W_hh0) | Wp1 524288 (frag-packed [W_ih1|W_hh1]) |
//   biasC 1024 (b_ih1 + b_hh1)
// Frag-pack: entry ((n*KB + kbi)*64 + L)*8 + e = W[j][k],
//   n = h16*4+g, j = g*256 + h16*16 + (L&15), k = kbi*32 + (L>>4)*8 + e.
__global__ __launch_bounds__(256) void cvt_weights(
    const float* __restrict__ W_hid, const float* __restrict__ W_ih0,
    const float* __restrict__ W_hh0, const float* __restrict__ W_ih1,
    const float* __restrict__ W_hh1, const float* __restrict__ b_ih1,
    const float* __restrict__ b_hh1,
    unsigned short* __restrict__ Whid_b, unsigned short* __restrict__ Wih0_b,
    unsigned short* __restrict__ Wp0, unsigned short* __restrict__ Wp1,
    float* __restrict__ biasC)
{
    int idx = blockIdx.x * 256 + threadIdx.x;
    if (idx < 65536) { Whid_b[idx] = f2bf(W_hid[idx]); return; }
    idx -= 65536;
    if (idx < 262144) {
        int gc = idx >> 8, k = idx & 255;
        Wih0_b[idx] = f2bf(W_ih0[gc * 258 + k]);
        return;
    }
    idx -= 262144;
    if (idx < 262144) {
        int p = idx;
        int e = p & 7, L = (p >> 3) & 63, kbi = (p >> 9) & 7, n = p >> 12;
        int h16 = n >> 2, g = n & 3;
        int j = g * 256 + h16 * 16 + (L & 15);
        int k = kbi * 32 + (L >> 4) * 8 + e;
        Wp0[p] = f2bf(W_hh0[j * 256 + k]);
        return;
    }
    idx -= 262144;
    if (idx < 524288) {
        int p = idx;
        int e = p & 7, L = (p >> 3) & 63, kbi = (p >> 9) & 15, n = p >> 13;
        int h16 = n >> 2, g = n & 3;
        int j = g * 256 + h16 * 16 + (L & 15);
        int k = kbi * 32 + (L >> 4) * 8 + e;
        float v = (k < 256) ? W_ih1[j * 256 + k] : W_hh1[j * 256 + (k - 256)];
        Wp1[p] = f2bf(v);
        return;
    }
    idx -= 524288;
    if (idx < 1024) biasC[idx] = b_ih1[idx] + b_hh1[idx];
}

// combined[n, c] : c<128 obs[b], c<192 lane[b], else ds[kk]
__global__ __launch_bounds__(256) void build_combined(
    const float* __restrict__ obs, const float* __restrict__ lane,
    const float* __restrict__ ds, unsigned short* __restrict__ comb)
{
    int idx = blockIdx.x * 256 + threadIdx.x;  // < 6144*256
    int n = idx >> 8, c = idx & 255;
    int b = n / 6, kk = n - b * 6;
    float v;
    if (c < 128)      v = obs[b * 128 + c];
    else if (c < 192) v = lane[b * 64 + (c - 128)];
    else              v = ds[kk * 64 + (c - 192)];
    comb[idx] = f2bf(v);
}

// ---------------- GEMM: hidden = leakyrelu(combined @ W_hid^T + b_hid) ----------------
__global__ __launch_bounds__(256) void gemm_hidden(
    const unsigned short* __restrict__ A, const unsigned short* __restrict__ B,
    const float* __restrict__ b_hid, unsigned short* __restrict__ hidden)
{
    int wid = threadIdx.x >> 6, lane = threadIdx.x & 63;
    int lrow = lane & 15, kg = lane >> 4;
    int r0 = blockIdx.x * 64;
    int c0 = wid * 64;
    f32x4 acc[4][4];
#pragma unroll
    for (int i = 0; i < 4; i++)
#pragma unroll
        for (int j = 0; j < 4; j++) acc[i][j] = f32x4{0.f, 0.f, 0.f, 0.f};

#pragma unroll
    for (int kb = 0; kb < 256; kb += 32) {
        int k = kb + kg * 8;
        short8 a[4], b[4];
#pragma unroll
        for (int mi = 0; mi < 4; mi++)
            a[mi] = *(const short8*)(A + (size_t)(r0 + mi * 16 + lrow) * 256 + k);
#pragma unroll
        for (int ni = 0; ni < 4; ni++)
            b[ni] = *(const short8*)(B + (size_t)(c0 + ni * 16 + lrow) * 256 + k);
#pragma unroll
        for (int mi = 0; mi < 4; mi++)
#pragma unroll
            for (int ni = 0; ni < 4; ni++)
                acc[mi][ni] = MFMA_BF16(a[mi], b[ni], acc[mi][ni]);
    }
#pragma unroll
    for (int mi = 0; mi < 4; mi++) {
#pragma unroll
        for (int ni = 0; ni < 4; ni++) {
            int col = c0 + ni * 16 + lrow;
            float bb = b_hid[col];
#pragma unroll
            for (int r = 0; r < 4; r++) {
                int row = r0 + mi * 16 + kg * 4 + r;
                float x = acc[mi][ni][r] + bb;
                x = x >= 0.f ? x : 0.1f * x;
                hidden[(size_t)row * 256 + col] = f2bf(x);
            }
        }
    }
}

// ---------------- endpoint / conf head (thread per row) ----------------
__global__ __launch_bounds__(256) void head_kernel(
    const unsigned short* __restrict__ hidden, const float* __restrict__ W_ep,
    const float* __restrict__ b_ep, const float* __restrict__ W_conf,
    const float* __restrict__ b_conf, float* __restrict__ out_conf,
    float* __restrict__ out_ep, float* __restrict__ ep_buf)
{
    int n = blockIdx.x * 256 + threadIdx.x;  // < 6144
    const unsigned short* hr = hidden + (size_t)n * 256;
    float e0 = 0.f, e1 = 0.f, cf = 0.f;
    for (int k = 0; k < 256; k += 8) {
        short8 hv = *(const short8*)(hr + k);
#pragma unroll
        for (int i = 0; i < 8; i++) {
            float h = bf2f((unsigned short)hv[i]);
            e0 += h * W_ep[k + i];
            e1 += h * W_ep[256 + k + i];
            cf += h * W_conf[k + i];
        }
    }
    e0 += b_ep[0]; e1 += b_ep[1]; cf += b_conf[0];
    out_conf[n] = cf;
    out_ep[2 * n] = e0; out_ep[2 * n + 1] = e1;
    ep_buf[2 * n] = e0; ep_buf[2 * n + 1] = e1;
}

// ---------------- GEMM: gx0 (b_ih0+b_hh0 folded, ep rank-2), bf16 frag-layout out ----
// Persistent block pb owns rows [pb*32, pb*32+32). Write:
// gxs4[((pb*8 + wv)*16 + ((mi&1)*2+ni2)*4 + g)*64 + lane], pb = bx*2 + (mi>>1).
__global__ __launch_bounds__(256) void gemm_gx0(
    const unsigned short* __restrict__ A, const unsigned short* __restrict__ B,
    const float* __restrict__ W_ih0f, const float* __restrict__ b_ih0,
    const float* __restrict__ b_hh0, const float* __restrict__ ep_buf,
    u16x4* __restrict__ gxs4)
{
    int wid = threadIdx.x >> 6, lane = threadIdx.x & 63;
    int lrow = lane & 15, kg = lane >> 4;
    int r0 = blockIdx.x * 64;
    int g  = blockIdx.y;                   // gate
    int c0 = g * 256 + wid * 64;
    f32x4 acc[4][4];
#pragma unroll
    for (int i = 0; i < 4; i++)
#pragma unroll
        for (int j = 0; j < 4; j++) acc[i][j] = f32x4{0.f, 0.f, 0.f, 0.f};

#pragma unroll
    for (int kb = 0; kb < 256; kb += 32) {
        int k = kb + kg * 8;
        short8 a[4], b[4];
#pragma unroll
        for (int mi = 0; mi < 4; mi++)
            a[mi] = *(const short8*)(A + (size_t)(r0 + mi * 16 + lrow) * 256 + k);
#pragma unroll
        for (int ni = 0; ni < 4; ni++)
            b[ni] = *(const short8*)(B + (size_t)(c0 + ni * 16 + lrow) * 256 + k);
#pragma unroll
        for (int mi = 0; mi < 4; mi++)
#pragma unroll
            for (int ni = 0; ni < 4; ni++)
                acc[mi][ni] = MFMA_BF16(a[mi], b[ni], acc[mi][ni]);
    }
#pragma unroll
    for (int mi = 0; mi < 4; mi++) {
#pragma unroll
        for (int ni = 0; ni < 4; ni++) {
            int gc = c0 + ni * 16 + lrow;
            float w256 = W_ih0f[(size_t)gc * 258 + 256];
            float w257 = W_ih0f[(size_t)gc * 258 + 257];
            float bb = b_ih0[gc] + b_hh0[gc];
            int h16 = wid * 4 + ni;
            int wv = h16 >> 1, ni2 = h16 & 1;
            int pb = blockIdx.x * 2 + (mi >> 1);
            int idx16 = ((mi & 1) * 2 + ni2) * 4 + g;
            u16x4 pv;
#pragma unroll
            for (int r = 0; r < 4; r++) {
                int row = r0 + mi * 16 + kg * 4 + r;
                float v = acc[mi][ni][r] + bb + ep_buf[2 * row] * w256 + ep_buf[2 * row + 1] * w257;
                pv[r] = f2bf(v);
            }
            gxs4[(size_t)((pb * 8 + wv) * 16 + idx16) * 64 + lane] = pv;
        }
    }
}

// ---------------- persistent 30-step LSTM --------
// 192 blocks x 512 threads (8 waves). Block owns 32 rows. Wave w: hcols [w*32, w*32+32).
// r9 structure + AGPR-pinned cell state:
//  - c0r/c1r (32 regs) parked in AGPRs between updates (PIN_AGPR) -> arch-VGPR
//    pressure ~108 < 128 -> zero spill (spill scratch was the L2 polluter r4-r9).
//  - gx staged in LDS once; weights stream from L2; bias from biasC per iter.
// LDS 128 KB: h0 pp @0/16KB, h1 pp @32/48KB (bf16, XOR swizzle col^((row&7)<<3)),
//             gx @64KB (u16x4[(w*16+j)*64+lane]).
// Iter i: phase A h0[i] (i<=29); phase B h1[i-1] (1<=i<=30); proj t=i-2 (2<=i<=31).
__global__ __launch_bounds__(512, 1) void lstm_persistent(
    const unsigned short* __restrict__ Wp0, const unsigned short* __restrict__ Wp1,
    const u16x4* __restrict__ gxs4, const float* __restrict__ biasC,
    const float* __restrict__ W_op, const float* __restrict__ b_op,
    float* __restrict__ out_final)
{
    __shared__ unsigned short lds[65536];   // 128 KB

    const int blk  = blockIdx.x;            // rows blk*32 .. +32
    const int w    = threadIdx.x >> 6;
    const int lane = threadIdx.x & 63;
    const int lrow = lane & 15;
    const int kg   = lane >> 4;
    const int sw   = (lrow & 7) << 3;       // A-frag k-swizzle

    // stage gx into LDS (once)
    u16x4* gxl = (u16x4*)&lds[32768];
    {
        const u16x4* gxw = gxs4 + (size_t)(blk * 8 + w) * 16 * 64;
#pragma unroll
        for (int j = 0; j < 16; j++)
            gxl[(w * 16 + j) * 64 + lane] = gxw[j * 64 + lane];
    }
    __syncthreads();

    f32x4 c0r[2][2], c1r[2][2];
#pragma unroll
    for (int mi = 0; mi < 2; mi++)
#pragma unroll
        for (int ni2 = 0; ni2 < 2; ni2++) {
            c0r[mi][ni2] = f32x4{0.f, 0.f, 0.f, 0.f};
            c1r[mi][ni2] = f32x4{0.f, 0.f, 0.f, 0.f};
            PIN_AGPR(c0r[mi][ni2]);
            PIN_AGPR(c1r[mi][ni2]);
        }

    // per-lane base pointers
    const unsigned short* wp0w = Wp0 + (size_t)w * 8 * 4096 + (size_t)lane * 8;
    const unsigned short* wp1w = Wp1 + (size_t)w * 8 * 8192 + (size_t)lane * 8;

    const int prow = threadIdx.x >> 4;   // 0..31 (proj row)
    const int pseg = threadIdx.x & 15;   // 16 threads/row, 16 cols each
    const int psw  = (prow & 7) << 3;

    for (int i = 0; i < 32; ++i) {
        // ---------- phase A: L0 step i ----------
        if (i <= 29) {
            unsigned short* h0new = lds + (i & 1) * 8192;
            const unsigned short* h0prev = lds + ((i - 1) & 1) * 8192;
#pragma unroll
            for (int half = 0; half < 2; half++) {
                f32x4 acc[2][4];
#pragma unroll
                for (int mi = 0; mi < 2; mi++)
#pragma unroll
                    for (int n = 0; n < 4; n++) acc[mi][n] = f32x4{0.f, 0.f, 0.f, 0.f};
                if (i > 0) {
#pragma unroll
                    for (int kbi = 0; kbi < 8; kbi++) {
                        short8 a[2], b[4];
#pragma unroll
                        for (int mi = 0; mi < 2; mi++) {
                            int k = (kbi * 32 + kg * 8) ^ sw;
                            a[mi] = *(const short8*)&h0prev[(mi * 16 + lrow) * 256 + k];
                        }
#pragma unroll
                        for (int g = 0; g < 4; g++)
                            b[g] = *(const short8*)&wp0w[(size_t)(((half * 4 + g) * 8 + kbi) * 64) * 8];
#pragma unroll
                        for (int mi = 0; mi < 2; mi++)
#pragma unroll
                            for (int g = 0; g < 4; g++)
                                acc[mi][g] = MFMA_BF16(a[mi], b[g], acc[mi][g]);
                    }
                }
                int col = w * 32 + half * 16 + lrow;
#pragma unroll
                for (int mi = 0; mi < 2; mi++) {
                    u16x4 gI = gxl[(w * 16 + (mi * 2 + half) * 4 + 0) * 64 + lane];
                    u16x4 gF = gxl[(w * 16 + (mi * 2 + half) * 4 + 1) * 64 + lane];
                    u16x4 gG = gxl[(w * 16 + (mi * 2 + half) * 4 + 2) * 64 + lane];
                    u16x4 gO = gxl[(w * 16 + (mi * 2 + half) * 4 + 3) * 64 + lane];
                    f32x4 cp = c0r[mi][half];
                    f32x4 cnv;
#pragma unroll
                    for (int r = 0; r < 4; r++) {
                        float gi = acc[mi][0][r] + bf2f(gI[r]);
                        float gf = acc[mi][1][r] + bf2f(gF[r]);
                        float gg = acc[mi][2][r] + bf2f(gG[r]);
                        float go = acc[mi][3][r] + bf2f(gO[r]);
                        float cn = sigm(gf) * cp[r] + sigm(gi) * tanh_(gg);
                        float hn = sigm(go) * tanh_(cn);
                        cnv[r] = cn;
                        int row = mi * 16 + kg * 4 + r;
                        h0new[row * 256 + (col ^ ((row & 7) << 3))] = f2bf(hn);
                    }
                    c0r[mi][half] = cnv;
                    PIN_AGPR(c0r[mi][half]);
                }
            }
        }
        // ---------- phase B: L1 step i-1 ----------
        if (i >= 1 && i <= 30) {
            const unsigned short* h0prev = lds + ((i - 1) & 1) * 8192;
            const unsigned short* h1prev = lds + 16384 + (i & 1) * 8192;
            unsigned short* h1new = lds + 16384 + ((i - 1) & 1) * 8192;
#pragma unroll
            for (int half = 0; half < 2; half++) {
                f32x4 acc[2][4];
#pragma unroll
                for (int mi = 0; mi < 2; mi++)
#pragma unroll
                    for (int n = 0; n < 4; n++) acc[mi][n] = f32x4{0.f, 0.f, 0.f, 0.f};
#pragma unroll
                for (int kbi = 0; kbi < 8; kbi++) {
                    short8 a[2], b[4];
#pragma unroll
                    for (int mi = 0; mi < 2; mi++) {
                        int k = (kbi * 32 + kg * 8) ^ sw;
                        a[mi] = *(const short8*)&h0prev[(mi * 16 + lrow) * 256 + k];
                    }
#pragma unroll
                    for (int g = 0; g < 4; g++)
                        b[g] = *(const short8*)&wp1w[(size_t)(((half * 4 + g) * 16 + kbi) * 64) * 8];
#pragma unroll
                    for (int mi = 0; mi < 2; mi++)
#pragma unroll
                        for (int g = 0; g < 4; g++)
                            acc[mi][g] = MFMA_BF16(a[mi], b[g], acc[mi][g]);
                }
                if (i >= 2) {
#pragma unroll
                    for (int kbi = 0; kbi < 8; kbi++) {
                        short8 a[2], b[4];
#pragma unroll
                        for (int mi = 0; mi < 2; mi++) {
                            int k = (kbi * 32 + kg * 8) ^ sw;
                            a[mi] = *(const short8*)&h1prev[(mi * 16 + lrow) * 256 + k];
                        }
#pragma unroll
                        for (int g = 0; g < 4; g++)
                            b[g] = *(const short8*)&wp1w[(size_t)(((half * 4 + g) * 16 + 8 + kbi) * 64) * 8];
#pragma unroll
                        for (int mi = 0; mi < 2; mi++)
#pragma unroll
                            for (int g = 0; g < 4; g++)
                                acc[mi][g] = MFMA_BF16(a[mi], b[g], acc[mi][g]);
                    }
                }
                int col = w * 32 + half * 16 + lrow;
                float bI = biasC[col];
                float bF = biasC[256 + col];
                float bG = biasC[512 + col];
                float bO = biasC[768 + col];
#pragma unroll
                for (int mi = 0; mi < 2; mi++) {
                    f32x4 cp = c1r[mi][half];
                    f32x4 cnv;
#pragma unroll
                    for (int r = 0; r < 4; r++) {
                        float gi = acc[mi][0][r] + bI;
                        float gf = acc[mi][1][r] + bF;
                        float gg = acc[mi][2][r] + bG;
                        float go = acc[mi][3][r] + bO;
                        float cn = sigm(gf) * cp[r] + sigm(gi) * tanh_(gg);
                        float hn = sigm(go) * tanh_(cn);
                        cnv[r] = cn;
                        int row = mi * 16 + kg * 4 + r;
                        h1new[row * 256 + (col ^ ((row & 7) << 3))] = f2bf(hn);
                    }
                    c1r[mi][half] = cnv;
                    PIN_AGPR(c1r[mi][half]);
                }
            }
        }
        // ---------- out-projection: t = i-2 ----------
        if (i >= 2) {
            const unsigned short* h1t = lds + 16384 + (i & 1) * 8192;
            float p0 = 0.f, p1 = 0.f;
#pragma unroll
            for (int q = 0; q < 2; q++) {
                int col0 = pseg * 16 + q * 8;
                short8 hv = *(const short8*)&h1t[prow * 256 + (col0 ^ psw)];
#pragma unroll
                for (int e = 0; e < 8; e++) {
                    float h = bf2f((unsigned short)hv[e]);
                    p0 += h * W_op[col0 + e];
                    p1 += h * W_op[256 + col0 + e];
                }
            }
#pragma unroll
            for (int s = 1; s < 16; s <<= 1) {
                p0 += __shfl_xor(p0, s, 64);
                p1 += __shfl_xor(p1, s, 64);
            }
            if (pseg == 0) {
                int grow = blk * 32 + prow;
                int t = i - 2;
                out_final[((size_t)grow * TT + t) * 2 + 0] = p0 + b_op[0];
                out_final[((size_t)grow * TT + t) * 2 + 1] = p1 + b_op[1];
            }
        }
        __syncthreads();
    }
}

// ---------------- host ----------------
extern "C" void kernel_launch(void* const* d_in, const int* in_sizes, int n_in,
                              void* d_out, int out_size, void* d_ws, size_t ws_size,
                              hipStream_t stream)
{
    const float* obs    = (const float*)d_in[0];
    const float* lane   = (const float*)d_in[1];
    const float* ds     = (const float*)d_in[3];
    const float* W_hid  = (const float*)d_in[4];
    const float* b_hid  = (const float*)d_in[5];
    const float* W_ep   = (const float*)d_in[6];
    const float* b_ep   = (const float*)d_in[7];
    const float* W_conf = (const float*)d_in[8];
    const float* b_conf = (const float*)d_in[9];
    const float* W_ih0  = (const float*)d_in[10];
    const float* W_hh0  = (const float*)d_in[11];
    const float* b_ih0  = (const float*)d_in[12];
    const float* b_hh0  = (const float*)d_in[13];
    const float* W_ih1  = (const float*)d_in[14];
    const float* W_hh1  = (const float*)d_in[15];
    const float* b_ih1  = (const float*)d_in[16];
    const float* b_hh1  = (const float*)d_in[17];
    const float* W_op   = (const float*)d_in[18];
    const float* b_op   = (const float*)d_in[19];

    float* out_final = (float*)d_out;           // [6144*30*2]
    float* out_conf  = out_final + 368640;      // [6144]
    float* out_ep    = out_conf + 6144;         // [6144*2]

    char* ws = (char*)d_ws;
    size_t off = 0;
    auto alloc = [&](size_t bytes) -> void* {
        void* p = ws + off;
        off += (bytes + 255) & ~(size_t)255;
        return p;
    };
    unsigned short* Whid_b = (unsigned short*)alloc(65536 * 2);
    unsigned short* Wih0_b = (unsigned short*)alloc(262144 * 2);
    unsigned short* Wp0    = (unsigned short*)alloc(262144 * 2);
    unsigned short* Wp1    = (unsigned short*)alloc(524288 * 2);
    float*          biasC  = (float*)alloc(1024 * 4);
    unsigned short* comb_b = (unsigned short*)alloc(1572864 * 2);
    unsigned short* hid_b  = (unsigned short*)alloc(1572864 * 2);
    float* ep_buf = (float*)alloc(12288 * 4);
    u16x4* gxs4   = (u16x4*)alloc((size_t)1572864 * 8);

    cvt_weights<<<4356, 256, 0, stream>>>(W_hid, W_ih0, W_hh0, W_ih1, W_hh1,
                                          b_ih1, b_hh1,
                                          Whid_b, Wih0_b, Wp0, Wp1, biasC);
    build_combined<<<6144, 256, 0, stream>>>(obs, lane, ds, comb_b);
    gemm_hidden<<<96, 256, 0, stream>>>(comb_b, Whid_b, b_hid, hid_b);
    head_kernel<<<24, 256, 0, stream>>>(hid_b, W_ep, b_ep, W_conf, b_conf,
                                        out_conf, out_ep, ep_buf);
    dim3 g2(96, 4);
    gemm_gx0<<<g2, 256, 0, stream>>>(hid_b, Wih0_b, W_ih0, b_ih0, b_hh0, ep_buf, gxs4);

    lstm_persistent<<<192, 512, 0, stream>>>(Wp0, Wp1, gxs4, biasC,
                                             W_op, b_op, out_final);
}